// Round 2
// baseline (816.752 us; speedup 1.0000x reference)
//
#include <hip/hip_runtime.h>

// vertices_to_edges: (B,V,C) f32 + (B,E,2) i32 -> (B,C,E) f32
// out[b][c][e] = 0.5*(vt[b][v1][c] + vt[b][v2][c])
//
// One thread per (b, e). Stores for a fixed c are coalesced across lanes
// (consecutive e), so the transpose needs no LDS. Gather reads are float2
// (rows are 8B-aligned: row byte offset = v*248, 248%8==0; float4 would be
// misaligned for odd v). vertex_tokens (148.8 MB) fits in the 256 MiB L3,
// so gather re-reads (avg degree 6) are L3 hits.

constexpr int Bc = 4;
constexpr int Vc = 150000;
constexpr int Ec = 450000;
constexpr int Cc = 62;

__global__ __launch_bounds__(256) void v2e_kernel(
    const float* __restrict__ vt,     // [B][V][C]
    const int*   __restrict__ edges,  // [B][E][2] (int32: JAX x64 off)
    float*       __restrict__ out)    // [B][C][E]
{
    const int e = blockIdx.x * 256 + threadIdx.x;
    const int b = blockIdx.y;
    if (e >= Ec) return;

    const int2 vv = *reinterpret_cast<const int2*>(edges + ((size_t)b * Ec + e) * 2);
    const float* __restrict__ r1 = vt + ((size_t)b * Vc + vv.x) * Cc;
    const float* __restrict__ r2 = vt + ((size_t)b * Vc + vv.y) * Cc;
    float* __restrict__ ob = out + (size_t)b * Cc * Ec + e;

#pragma unroll
    for (int c = 0; c < Cc; c += 2) {
        const float2 a = *reinterpret_cast<const float2*>(r1 + c);
        const float2 d = *reinterpret_cast<const float2*>(r2 + c);
        ob[(size_t)c       * Ec] = (a.x + d.x) * 0.5f;
        ob[(size_t)(c + 1) * Ec] = (a.y + d.y) * 0.5f;
    }
}

extern "C" void kernel_launch(void* const* d_in, const int* in_sizes, int n_in,
                              void* d_out, int out_size, void* d_ws, size_t ws_size,
                              hipStream_t stream) {
    const float* vt    = (const float*)d_in[0];
    const int*   edges = (const int*)d_in[1];
    float*       out   = (float*)d_out;

    dim3 grid((Ec + 255) / 256, Bc);
    v2e_kernel<<<grid, 256, 0, stream>>>(vt, edges, out);
}

// Round 6
// 666.528 us; speedup vs baseline: 1.2254x; 1.2254x over previous
//
#include <hip/hip_runtime.h>

// vertices_to_edges: (B,V,C) f32 + (B,E,2) i32 -> (B,C,E) f32
// out[b][c][e] = 0.5*(vt[b][v1][c] + vt[b][v2][c])
//
// Round-2 restructure: wave-cooperative gathers. Lane c reads vt[row][c], so
// each vertex row (248 B contiguous) is ONE coalesced wave load (4-5 cache
// lines) instead of 31 per-thread float2 loads that thrash L1 and multiply
// L2 request traffic ~6x. Edge sums land in a padded LDS tile [C][TE]
// (pitch 130 -> only 2-way bank aliasing, free per m136), then each channel
// row is written to out[b][c][e0..] as a coalesced float2 wave store.

constexpr int Bc = 4;
constexpr int Vc = 150000;
constexpr int Ec = 450000;
constexpr int Cc = 62;
constexpr int TE = 128;        // edges per block
constexpr int PITCH = TE + 2;  // even (8B-aligned float2 LDS reads), 2-way banks only

__global__ __launch_bounds__(256) void v2e_kernel(
    const float* __restrict__ vt,     // [B][V][C]
    const int*   __restrict__ edges,  // [B][E][2]
    float*       __restrict__ out)    // [B][C][E]
{
    __shared__ float tile[Cc * PITCH];   // 32240 B
    __shared__ int2  eidx[TE];           // 1 KB

    const int b  = blockIdx.y;
    const int e0 = blockIdx.x * TE;
    const int nE = min(TE, Ec - e0);
    const int t    = threadIdx.x;
    const int wave = t >> 6;
    const int lane = t & 63;

    // Stage the block's edge pairs (coalesced int2 loads).
    if (t < nE)
        eidx[t] = *reinterpret_cast<const int2*>(edges + ((size_t)b * Ec + e0 + t) * 2);
    __syncthreads();

    // Phase 1: wave w sums edges [w*32, w*32+32). Lane c holds channel c.
    const float* __restrict__ vb = vt + (size_t)b * Vc * Cc;
    const int iBeg = wave * 32;
    const int iEnd = min(iBeg + 32, nE);
#pragma unroll 4
    for (int i = iBeg; i < iEnd; ++i) {
        const int2 vv = eidx[i];   // uniform-address LDS broadcast
        if (lane < Cc) {
            const float a = vb[(size_t)vv.x * Cc + lane];
            const float d = vb[(size_t)vv.y * Cc + lane];
            tile[lane * PITCH + i] = (a + d) * 0.5f;
        }
    }
    __syncthreads();

    // Phase 2: coalesced channel-row stores. Wave w handles c = w, w+4, ...
    float* __restrict__ ob = out + (size_t)b * Cc * Ec + e0;
    if (nE == TE) {
        for (int c = wave; c < Cc; c += 4) {
            const float2 v = *reinterpret_cast<const float2*>(&tile[c * PITCH + 2 * lane]);
            *reinterpret_cast<float2*>(ob + (size_t)c * Ec + 2 * lane) = v;
        }
    } else {
        for (int c = wave; c < Cc; c += 4)
            for (int e = lane; e < nE; e += 64)
                ob[(size_t)c * Ec + e] = tile[c * PITCH + e];
    }
}

extern "C" void kernel_launch(void* const* d_in, const int* in_sizes, int n_in,
                              void* d_out, int out_size, void* d_ws, size_t ws_size,
                              hipStream_t stream) {
    const float* vt    = (const float*)d_in[0];
    const int*   edges = (const int*)d_in[1];
    float*       out   = (float*)d_out;

    dim3 grid((Ec + TE - 1) / TE, Bc);
    v2e_kernel<<<grid, 256, 0, stream>>>(vt, edges, out);
}